// Round 1
// baseline (6403.849 us; speedup 1.0000x reference)
//
#include <hip/hip_runtime.h>
#include <cstdint>

// Problem dims (fixed by reference)
#define NB    1024      // batch
#define TT    64        // time steps
#define DIN   512       // input dim
#define HD    1024      // hidden dim
#define FH    4096      // 4*H
#define KTOT  2560      // D + 2H

typedef _Float16 half8 __attribute__((ext_vector_type(8)));
typedef float floatx4 __attribute__((ext_vector_type(4)));

// ---- workspace layout (bytes). Total = 117,440,512 (112 MB) ----
#define OFF_WT    ((size_t)0)            // f16 Wt[4096][2560]           20,971,520
#define OFF_X16   ((size_t)20971520)     // f16 x[1024][64][512]         67,108,864
#define OFF_H16   ((size_t)88080384)     // f16 h[1024][1024]             2,097,152
#define OFF_AT16  ((size_t)90177536)     // f16 attn[1024][1024]          2,097,152
#define OFF_HF    ((size_t)92274688)     // f32 h[1024][1024]             4,194,304
#define OFF_C     ((size_t)96468992)     // f32 c[1024][1024]             4,194,304
#define OFF_ABUF  ((size_t)100663296)    // f32 a[1024][4096]            16,777,216

__device__ __forceinline__ void async_copy16(const void* g, void* l) {
    // global -> LDS direct copy, 16B per lane. LDS dest is wave-uniform base;
    // HW strides lane*16. (CK-style address-space casts via uintptr_t.)
    __builtin_amdgcn_global_load_lds(
        (const __attribute__((address_space(1))) void*)(uintptr_t)g,
        (__attribute__((address_space(3))) void*)(uintptr_t)l,
        16, 0, 0);
}

// ---------- one-time: W = [Wx;Wh;Wattn] (2560x4096 f32) -> Wt (4096x2560 f16) ----------
__global__ void k_convert_w(const float* __restrict__ Wx, const float* __restrict__ Wh,
                            const float* __restrict__ Wattn, _Float16* __restrict__ Wt) {
    __shared__ float tile[32][33];             // +1 pad: no bank conflicts
    const int k0 = blockIdx.x * 32;            // K in [0,2560)
    const int c0 = blockIdx.y * 32;            // out-col in [0,4096)
    const int tx = threadIdx.x & 31;
    const int ty = threadIdx.x >> 5;           // 0..7
    const float* src; int kb;
    if (k0 < 512)       { src = Wx;    kb = k0; }
    else if (k0 < 1536) { src = Wh;    kb = k0 - 512; }
    else                { src = Wattn; kb = k0 - 1536; }
    #pragma unroll
    for (int r = ty; r < 32; r += 8)
        tile[r][tx] = src[(size_t)(kb + r) * FH + c0 + tx];
    __syncthreads();
    #pragma unroll
    for (int r = ty; r < 32; r += 8)
        Wt[(size_t)(c0 + r) * KTOT + k0 + tx] = (_Float16)tile[tx][r];
}

// ---------- one-time: x f32 -> f16 ----------
__global__ void k_convert_x(const float* __restrict__ x, _Float16* __restrict__ xh) {
    const size_t i = ((size_t)blockIdx.x * 256 + threadIdx.x) * 8;
    float4 v0 = *(const float4*)(x + i);
    float4 v1 = *(const float4*)(x + i + 4);
    half8 h;
    h[0] = (_Float16)v0.x; h[1] = (_Float16)v0.y; h[2] = (_Float16)v0.z; h[3] = (_Float16)v0.w;
    h[4] = (_Float16)v1.x; h[5] = (_Float16)v1.y; h[6] = (_Float16)v1.z; h[7] = (_Float16)v1.w;
    *(half8*)(xh + i) = h;
}

// ---------- one-time: h0 = c0 = mean(A over 16 cells) ----------
__global__ void k_init(const float* __restrict__ A, float* __restrict__ hf,
                       _Float16* __restrict__ h16, float* __restrict__ c) {
    const int idx = blockIdx.x * 256 + threadIdx.x;     // n*1024 + h
    const float* a = A + (size_t)idx * 16;
    float s = 0.f;
    #pragma unroll
    for (int l = 0; l < 16; l++) s += a[l];
    const float m = s * (1.0f / 16.0f);
    hf[idx] = m; h16[idx] = (_Float16)m; c[idx] = m;
}

// ---------- per step: scores -> softmax -> attn (all fp32), emit attn as f16 ----------
__global__ void k_attn(const float* __restrict__ A, const float* __restrict__ hf,
                       _Float16* __restrict__ at16) {
    const int n = blockIdx.x;
    const int tid = threadIdx.x, lane = tid & 63, wid = tid >> 6;
    const float* An = A + (size_t)n * (HD * 16);
    float s[16];
    #pragma unroll
    for (int l = 0; l < 16; l++) s[l] = 0.f;
    for (int h = tid; h < HD; h += 256) {
        const float hv = hf[n * HD + h];
        const float* af = An + h * 16;
        #pragma unroll
        for (int l = 0; l < 16; l++) s[l] += hv * af[l];
    }
    #pragma unroll
    for (int l = 0; l < 16; l++)
        for (int off = 32; off > 0; off >>= 1) s[l] += __shfl_down(s[l], off, 64);
    __shared__ float red[4][16];
    __shared__ float wsm[16];
    if (lane == 0) {
        #pragma unroll
        for (int l = 0; l < 16; l++) red[wid][l] = s[l];
    }
    __syncthreads();
    if (tid == 0) {
        float sc[16]; float mx = -1e30f;
        #pragma unroll
        for (int l = 0; l < 16; l++) {
            sc[l] = (red[0][l] + red[1][l] + red[2][l] + red[3][l]) * 0.03125f; // 1/sqrt(1024)
            mx = fmaxf(mx, sc[l]);
        }
        float sum = 0.f;
        #pragma unroll
        for (int l = 0; l < 16; l++) { sc[l] = expf(sc[l] - mx); sum += sc[l]; }
        const float inv = 1.0f / sum;
        #pragma unroll
        for (int l = 0; l < 16; l++) wsm[l] = sc[l] * inv;
    }
    __syncthreads();
    float wr[16];
    #pragma unroll
    for (int l = 0; l < 16; l++) wr[l] = wsm[l];
    for (int h = tid; h < HD; h += 256) {
        const float* af = An + h * 16;
        float v = 0.f;
        #pragma unroll
        for (int l = 0; l < 16; l++) v += af[l] * wr[l];
        at16[n * HD + h] = (_Float16)v;
    }
}

// ---------- per step: a = [x_t | h | attn] (1024x2560) * Wt^T (->1024x4096), f16 MFMA ----------
__launch_bounds__(256)
__global__ void k_gemm(const _Float16* __restrict__ xh, const _Float16* __restrict__ h16,
                       const _Float16* __restrict__ at16, const _Float16* __restrict__ Wt,
                       float* __restrict__ abuf, int t) {
    __shared__ _Float16 As[128 * 32];   // [row][k], 8 KB
    __shared__ _Float16 Bs[128 * 32];   // [out-col][k], 8 KB
    const int tid  = threadIdx.x;
    const int lane = tid & 63;
    const int w    = tid >> 6;          // wave 0..3
    const int wm   = w >> 1, wn = w & 1;
    const int bm0  = blockIdx.x * 128;  // batch rows
    const int bn0  = blockIdx.y * 128;  // out cols

    const int srow_in_q = lane >> 2;       // 0..15
    const int scol      = (lane & 3) * 8;  // k chunk within 32

    floatx4 acc[4][4];
    #pragma unroll
    for (int i = 0; i < 4; i++)
        #pragma unroll
        for (int j = 0; j < 4; j++) acc[i][j] = (floatx4)0.0f;

    for (int k0 = 0; k0 < KTOT; k0 += 32) {
        // A-operand segment select (uniform per iteration: boundaries are k-multiples of 32)
        const _Float16* abase; int astride, klocal;
        if (k0 < DIN)            { abase = xh + (size_t)t * DIN; astride = TT * DIN; klocal = k0; }
        else if (k0 < DIN + HD)  { abase = h16;  astride = HD; klocal = k0 - DIN; }
        else                     { abase = at16; astride = HD; klocal = k0 - DIN - HD; }
        #pragma unroll
        for (int q = 0; q < 2; q++) {
            const int row = w * 32 + q * 16 + srow_in_q;
            async_copy16(abase + (size_t)(bm0 + row) * astride + klocal + scol,
                         &As[w * 1024 + q * 512]);
        }
        #pragma unroll
        for (int q = 0; q < 2; q++) {
            const int row = w * 32 + q * 16 + srow_in_q;
            async_copy16(Wt + (size_t)(bn0 + row) * KTOT + k0 + scol,
                         &Bs[w * 1024 + q * 512]);
        }
        __syncthreads();
        const int kq = (lane >> 4) * 8;
        const int rr = lane & 15;
        half8 af[4], bf[4];
        #pragma unroll
        for (int i = 0; i < 4; i++) af[i] = *(const half8*)&As[(wm * 64 + i * 16 + rr) * 32 + kq];
        #pragma unroll
        for (int j = 0; j < 4; j++) bf[j] = *(const half8*)&Bs[(wn * 64 + j * 16 + rr) * 32 + kq];
        #pragma unroll
        for (int i = 0; i < 4; i++)
            #pragma unroll
            for (int j = 0; j < 4; j++)
                acc[i][j] = __builtin_amdgcn_mfma_f32_16x16x32_f16(af[i], bf[j], acc[i][j], 0, 0, 0);
        __syncthreads();
    }
    // epilogue: C/D layout col=lane&15, row=quad*4+reg (dtype-independent, HW-verified)
    const int q4 = (lane >> 4) * 4;
    const int cn = lane & 15;
    #pragma unroll
    for (int i = 0; i < 4; i++)
        #pragma unroll
        for (int j = 0; j < 4; j++)
            #pragma unroll
            for (int r = 0; r < 4; r++) {
                const int row = bm0 + wm * 64 + i * 16 + q4 + r;
                const int col = bn0 + wn * 64 + j * 16 + cn;
                abuf[(size_t)row * FH + col] = acc[i][j][r];
            }
}

// ---------- per step: LSTM cell (fp32), writes out[:,t,:], h (f32+f16), c ----------
__global__ void k_cell(const float* __restrict__ abuf, const float* __restrict__ b,
                       float* __restrict__ c, float* __restrict__ hf,
                       _Float16* __restrict__ h16, float* __restrict__ out, int t) {
    const int idx = blockIdx.x * 256 + threadIdx.x;   // n*1024 + j
    const int n = idx >> 10, j = idx & 1023;
    const size_t base = (size_t)n * FH + j;
    const float ai = abuf[base]          + b[j];
    const float af = abuf[base + 1024]   + b[j + 1024];
    const float ao = abuf[base + 2048]   + b[j + 2048];
    const float ag = abuf[base + 3072]   + b[j + 3072];
    const float ig = 1.0f / (1.0f + expf(-ai));
    const float fg = 1.0f / (1.0f + expf(-af));
    const float og = 1.0f / (1.0f + expf(-ao));
    const float gg = tanhf(ag);
    const float cn = fg * c[idx] + ig * gg;
    c[idx] = cn;
    const float hn = og * tanhf(cn);
    hf[idx] = hn;
    h16[idx] = (_Float16)hn;
    out[(size_t)n * (TT * HD) + (size_t)t * HD + j] = hn;
}

extern "C" void kernel_launch(void* const* d_in, const int* in_sizes, int n_in,
                              void* d_out, int out_size, void* d_ws, size_t ws_size,
                              hipStream_t stream) {
    const float* x     = (const float*)d_in[0];
    const float* A     = (const float*)d_in[1];
    const float* Wx    = (const float*)d_in[2];
    const float* Wh    = (const float*)d_in[3];
    const float* Wattn = (const float*)d_in[4];
    const float* b     = (const float*)d_in[5];
    float* out = (float*)d_out;

    uint8_t* ws = (uint8_t*)d_ws;
    _Float16* Wt   = (_Float16*)(ws + OFF_WT);
    _Float16* x16  = (_Float16*)(ws + OFF_X16);
    _Float16* h16  = (_Float16*)(ws + OFF_H16);
    _Float16* at16 = (_Float16*)(ws + OFF_AT16);
    float*    hf   = (float*)(ws + OFF_HF);
    float*    c    = (float*)(ws + OFF_C);
    float*    abuf = (float*)(ws + OFF_ABUF);

    k_convert_w<<<dim3(KTOT / 32, FH / 32), 256, 0, stream>>>(Wx, Wh, Wattn, Wt);
    k_convert_x<<<(NB * TT * DIN) / (256 * 8), 256, 0, stream>>>(x, x16);
    k_init<<<(NB * HD) / 256, 256, 0, stream>>>(A, hf, h16, c);

    for (int t = 0; t < TT; t++) {
        k_attn<<<NB, 256, 0, stream>>>(A, hf, at16);
        k_gemm<<<dim3(NB / 128, FH / 128), 256, 0, stream>>>(x16, h16, at16, Wt, abuf, t);
        k_cell<<<(NB * HD) / 256, 256, 0, stream>>>(abuf, b, c, hf, h16, out, t);
    }
}

// Round 2
// 4019.398 us; speedup vs baseline: 1.5932x; 1.5932x over previous
//
#include <hip/hip_runtime.h>
#include <cstdint>

// Problem dims (fixed by reference)
#define NB    1024      // batch
#define TT    64        // time steps
#define DIN   512       // input dim
#define HD    1024      // hidden dim
#define FH    4096      // 4*H
#define KTOT  2560      // D + 2H

typedef _Float16 half8 __attribute__((ext_vector_type(8)));
typedef float floatx4 __attribute__((ext_vector_type(4)));

// ---- workspace layout (bytes). Total = 150,994,944 (144 MB) ----
#define OFF_WT    ((size_t)0)            // f16 Wt[4096][2560]          20,971,520
#define OFF_X16   ((size_t)20971520)     // f16 x[1024][64][512]        67,108,864
#define OFF_A16   ((size_t)88080384)     // f16 A[1024][1024][16]       33,554,432
#define OFF_H16   ((size_t)121634816)    // f16 h[1024][1024]            2,097,152
#define OFF_AT16  ((size_t)123731968)    // f16 attn[1024][1024]         2,097,152
#define OFF_HF    ((size_t)125829120)    // f32 h0[1024][1024]           4,194,304
#define OFF_C     ((size_t)130023424)    // f32 c[1024][1024]            4,194,304
#define OFF_ABUF  ((size_t)134217728)    // f32 a[1024][4096]           16,777,216

__device__ __forceinline__ void async_copy16(const void* g, void* l) {
    // global -> LDS direct copy, 16B/lane. LDS dest is wave-uniform base;
    // HW strides lane*16.
    __builtin_amdgcn_global_load_lds(
        (const __attribute__((address_space(1))) void*)(uintptr_t)g,
        (__attribute__((address_space(3))) void*)(uintptr_t)l,
        16, 0, 0);
}

// ---------- one-time: W = [Wx;Wh;Wattn] (2560x4096 f32) -> Wt (4096x2560 f16) ----------
__global__ void k_convert_w(const float* __restrict__ Wx, const float* __restrict__ Wh,
                            const float* __restrict__ Wattn, _Float16* __restrict__ Wt) {
    __shared__ float tile[32][33];
    const int k0 = blockIdx.x * 32;            // K in [0,2560)
    const int c0 = blockIdx.y * 32;            // out-col in [0,4096)
    const int tx = threadIdx.x & 31;
    const int ty = threadIdx.x >> 5;           // 0..7
    const float* src; int kb;
    if (k0 < 512)       { src = Wx;    kb = k0; }
    else if (k0 < 1536) { src = Wh;    kb = k0 - 512; }
    else                { src = Wattn; kb = k0 - 1536; }
    #pragma unroll
    for (int r = ty; r < 32; r += 8)
        tile[r][tx] = src[(size_t)(kb + r) * FH + c0 + tx];
    __syncthreads();
    #pragma unroll
    for (int r = ty; r < 32; r += 8)
        Wt[(size_t)(c0 + r) * KTOT + k0 + tx] = (_Float16)tile[tx][r];
}

// ---------- one-time: f32 -> f16 bulk convert (x and A) ----------
__global__ void k_convert(const float* __restrict__ src, _Float16* __restrict__ dst) {
    const size_t i = ((size_t)blockIdx.x * 256 + threadIdx.x) * 8;
    float4 v0 = *(const float4*)(src + i);
    float4 v1 = *(const float4*)(src + i + 4);
    half8 h;
    h[0] = (_Float16)v0.x; h[1] = (_Float16)v0.y; h[2] = (_Float16)v0.z; h[3] = (_Float16)v0.w;
    h[4] = (_Float16)v1.x; h[5] = (_Float16)v1.y; h[6] = (_Float16)v1.z; h[7] = (_Float16)v1.w;
    *(half8*)(dst + i) = h;
}

// ---------- one-time: h0 = c0 = mean(A over 16 cells) ----------
__global__ void k_init(const float* __restrict__ A, float* __restrict__ hf,
                       _Float16* __restrict__ h16, float* __restrict__ c) {
    const int idx = blockIdx.x * 256 + threadIdx.x;     // n*1024 + h
    const float* a = A + (size_t)idx * 16;
    float s = 0.f;
    #pragma unroll
    for (int l = 0; l < 16; l++) s += a[l];
    const float m = s * (1.0f / 16.0f);
    hf[idx] = m; h16[idx] = (_Float16)m; c[idx] = m;
}

// ---------- attention core: h values provided per-thread via hs[] LDS ----------
// block = one batch row n; 256 threads, each owns h-rows r = kk*256+tid (kk=0..3)
__device__ __forceinline__ void attn_phase(const _Float16* __restrict__ A16, int n,
                                           const float* hs /*LDS, 1024*/,
                                           float red[4][16] /*LDS*/,
                                           _Float16* __restrict__ at16) {
    const int tid = threadIdx.x, lane = tid & 63, wid = tid >> 6;
    float s[16];
    #pragma unroll
    for (int l = 0; l < 16; l++) s[l] = 0.f;
    half8 a0[4], a1[4];
    #pragma unroll
    for (int kk = 0; kk < 4; kk++) {
        const int r = kk * 256 + tid;
        const _Float16* ap = A16 + ((size_t)n * HD + r) * 16;
        a0[kk] = *(const half8*)ap;
        a1[kk] = *(const half8*)(ap + 8);
        const float hv = hs[r];
        #pragma unroll
        for (int l = 0; l < 8; l++) {
            s[l]     += hv * (float)a0[kk][l];
            s[l + 8] += hv * (float)a1[kk][l];
        }
    }
    #pragma unroll
    for (int l = 0; l < 16; l++)
        #pragma unroll
        for (int off = 32; off > 0; off >>= 1) s[l] += __shfl_down(s[l], off, 64);
    if (lane == 0) {
        #pragma unroll
        for (int l = 0; l < 16; l++) red[wid][l] = s[l];
    }
    __syncthreads();
    // every thread computes the 16-wide softmax redundantly (no serial section)
    float w[16]; float mx = -1e30f;
    #pragma unroll
    for (int l = 0; l < 16; l++) {
        w[l] = (red[0][l] + red[1][l] + red[2][l] + red[3][l]) * 0.03125f; // 1/sqrt(1024)
        mx = fmaxf(mx, w[l]);
    }
    float sum = 0.f;
    #pragma unroll
    for (int l = 0; l < 16; l++) { w[l] = __expf(w[l] - mx); sum += w[l]; }
    const float inv = 1.0f / sum;
    #pragma unroll
    for (int l = 0; l < 16; l++) w[l] *= inv;
    #pragma unroll
    for (int kk = 0; kk < 4; kk++) {
        const int r = kk * 256 + tid;
        float v = 0.f;
        #pragma unroll
        for (int l = 0; l < 8; l++) v += (float)a0[kk][l] * w[l] + (float)a1[kk][l] * w[l + 8];
        at16[(size_t)n * HD + r] = (_Float16)v;
    }
}

// ---------- t=0 bootstrap: attn from h0 (hf) ----------
__global__ void k_attn_boot(const _Float16* __restrict__ A16, const float* __restrict__ hf,
                            _Float16* __restrict__ at16) {
    __shared__ float hs[HD];
    __shared__ float red[4][16];
    const int n = blockIdx.x, tid = threadIdx.x;
    #pragma unroll
    for (int kk = 0; kk < 4; kk++) {
        const int r = kk * 256 + tid;
        hs[r] = hf[(size_t)n * HD + r];
    }
    __syncthreads();
    attn_phase(A16, n, hs, red, at16);
}

// ---------- per step: LSTM cell (t) + attention (t+1), block per batch row ----------
__global__ void k_cellattn(const float* __restrict__ abuf, const float* __restrict__ b,
                           const _Float16* __restrict__ A16,
                           float* __restrict__ c, _Float16* __restrict__ h16,
                           _Float16* __restrict__ at16, float* __restrict__ out, int t) {
    __shared__ float hs[HD];
    __shared__ float red[4][16];
    const int n = blockIdx.x, tid = threadIdx.x;
    #pragma unroll
    for (int kk = 0; kk < 4; kk++) {
        const int j = kk * 256 + tid;
        const size_t base = (size_t)n * FH + j;
        const float ai = abuf[base]        + b[j];
        const float af = abuf[base + 1024] + b[j + 1024];
        const float ao = abuf[base + 2048] + b[j + 2048];
        const float ag = abuf[base + 3072] + b[j + 3072];
        const float ig = 1.0f / (1.0f + __expf(-ai));
        const float fg = 1.0f / (1.0f + __expf(-af));
        const float og = 1.0f / (1.0f + __expf(-ao));
        const float gg = tanhf(ag);
        const int idx = n * HD + j;
        const float cn = fg * c[idx] + ig * gg;
        c[idx] = cn;
        const float hn = og * tanhf(cn);
        hs[j] = hn;
        h16[idx] = (_Float16)hn;
        out[(size_t)n * (TT * HD) + (size_t)t * HD + j] = hn;
    }
    if (t == TT - 1) return;       // uniform: no attn needed after last step
    __syncthreads();
    attn_phase(A16, n, hs, red, at16);
}

// ---------- per step: a = [x_t | h | attn] (1024x2560) * Wt^T -> 1024x4096 ----------
// 128x128 tile, double-buffered pairs of BK=32 slabs, ONE barrier per 64-k:
// stores for iter k+1 are issued AFTER iter k's barrier, drained at iter k+1's
// barrier -> the compiler's vmcnt(0)-at-barrier lands ~1 compute-block after
// issue (hides most of the global->LDS latency; round-1 exposed it fully).
__launch_bounds__(256)
__global__ void k_gemm(const _Float16* __restrict__ xh, const _Float16* __restrict__ h16,
                       const _Float16* __restrict__ at16, const _Float16* __restrict__ Wt,
                       float* __restrict__ abuf, int t) {
    __shared__ _Float16 As[2][2][128 * 32];   // [pair][slab][row][k]  32 KB
    __shared__ _Float16 Bs[2][2][128 * 32];   //                       32 KB
    const int tid  = threadIdx.x;
    const int lane = tid & 63;
    const int w    = tid >> 6;
    const int wm   = w >> 1, wn = w & 1;
    const int bm0  = blockIdx.x * 128;  // batch rows
    const int bn0  = blockIdx.y * 128;  // out cols
    const int srow = lane >> 2;         // 0..15
    const int scol = (lane & 3) * 8;    // f16 offset within 32-k slab

    auto stage = [&](int kb, int pp) {  // issue stores for 64-k block [kb,kb+64) -> pair pp
        const _Float16* abase; int astride, klocal;
        if (kb < DIN)           { abase = xh + (size_t)t * DIN; astride = TT * DIN; klocal = kb; }
        else if (kb < DIN + HD) { abase = h16;  astride = HD; klocal = kb - DIN; }
        else                    { abase = at16; astride = HD; klocal = kb - DIN - HD; }
        #pragma unroll
        for (int s = 0; s < 2; s++) {
            #pragma unroll
            for (int q = 0; q < 2; q++) {
                const int row = w * 32 + q * 16 + srow;
                async_copy16(abase + (size_t)(bm0 + row) * astride + klocal + s * 32 + scol,
                             &As[pp][s][(w * 32 + q * 16) * 32]);
                async_copy16(Wt + (size_t)(bn0 + row) * KTOT + kb + s * 32 + scol,
                             &Bs[pp][s][(w * 32 + q * 16) * 32]);
            }
        }
    };

    floatx4 acc[4][4];
    #pragma unroll
    for (int i = 0; i < 4; i++)
        #pragma unroll
        for (int j = 0; j < 4; j++) acc[i][j] = (floatx4)0.0f;

    stage(0, 0);
    const int kq = (lane >> 4) * 8;
    const int rr = lane & 15;
    for (int it = 0; it < KTOT / 64; it++) {
        const int p = it & 1;
        __syncthreads();                       // drains pair-p stores (vmcnt(0))
        if (it < KTOT / 64 - 1) stage((it + 1) * 64, p ^ 1);   // hidden behind compute below
        #pragma unroll
        for (int s = 0; s < 2; s++) {
            half8 af[4], bf[4];
            #pragma unroll
            for (int i = 0; i < 4; i++)
                af[i] = *(const half8*)&As[p][s][(wm * 64 + i * 16 + rr) * 32 + kq];
            #pragma unroll
            for (int j = 0; j < 4; j++)
                bf[j] = *(const half8*)&Bs[p][s][(wn * 64 + j * 16 + rr) * 32 + kq];
            #pragma unroll
            for (int i = 0; i < 4; i++)
                #pragma unroll
                for (int j = 0; j < 4; j++)
                    acc[i][j] = __builtin_amdgcn_mfma_f32_16x16x32_f16(af[i], bf[j], acc[i][j], 0, 0, 0);
        }
    }
    // epilogue: C/D layout col=lane&15, row=quad*4+reg
    const int q4 = (lane >> 4) * 4;
    const int cn = lane & 15;
    #pragma unroll
    for (int i = 0; i < 4; i++)
        #pragma unroll
        for (int j = 0; j < 4; j++)
            #pragma unroll
            for (int r = 0; r < 4; r++) {
                const int row = bm0 + wm * 64 + i * 16 + q4 + r;
                const int col = bn0 + wn * 64 + j * 16 + cn;
                abuf[(size_t)row * FH + col] = acc[i][j][r];
            }
}

extern "C" void kernel_launch(void* const* d_in, const int* in_sizes, int n_in,
                              void* d_out, int out_size, void* d_ws, size_t ws_size,
                              hipStream_t stream) {
    const float* x     = (const float*)d_in[0];
    const float* A     = (const float*)d_in[1];
    const float* Wx    = (const float*)d_in[2];
    const float* Wh    = (const float*)d_in[3];
    const float* Wattn = (const float*)d_in[4];
    const float* b     = (const float*)d_in[5];
    float* out = (float*)d_out;

    uint8_t* ws = (uint8_t*)d_ws;
    _Float16* Wt   = (_Float16*)(ws + OFF_WT);
    _Float16* x16  = (_Float16*)(ws + OFF_X16);
    _Float16* A16  = (_Float16*)(ws + OFF_A16);
    _Float16* h16  = (_Float16*)(ws + OFF_H16);
    _Float16* at16 = (_Float16*)(ws + OFF_AT16);
    float*    hf   = (float*)(ws + OFF_HF);
    float*    c    = (float*)(ws + OFF_C);
    float*    abuf = (float*)(ws + OFF_ABUF);

    k_convert_w<<<dim3(KTOT / 32, FH / 32), 256, 0, stream>>>(Wx, Wh, Wattn, Wt);
    k_convert<<<(NB * TT * DIN) / 2048, 256, 0, stream>>>(x, x16);
    k_convert<<<(NB * HD * 16) / 2048, 256, 0, stream>>>(A, A16);
    k_init<<<(NB * HD) / 256, 256, 0, stream>>>(A, hf, h16, c);
    k_attn_boot<<<NB, 256, 0, stream>>>(A16, hf, at16);

    for (int t = 0; t < TT; t++) {
        k_gemm<<<dim3(NB / 128, FH / 128), 256, 0, stream>>>(x16, h16, at16, Wt, abuf, t);
        k_cellattn<<<NB, 256, 0, stream>>>(abuf, b, A16, c, h16, at16, out, t);
    }
}